// Round 1
// 2116.592 us; speedup vs baseline: 1.0721x; 1.0721x over previous
//
#include <hip/hip_runtime.h>

#define NLAYER 3
#define BB 16
#define DD 1024
#define HH 16
#define HDIM 64
#define TPAST 1023
#define TTOT 1024
#define SENC 1024
#define FFD 4096
#define VOUT 20
#define ASCALE 0.125f
#define LNEPS 1e-5f
#define NS 8
#define CH 128   /* TTOT / NS */

// ---------------------------------------------------------------------------
// Cacc[16, N] += X[16, K-slice] @ W[K-slice, N]   (atomic, C pre-zeroed)
// ---------------------------------------------------------------------------
#define KSL 128
__global__ __launch_bounds__(64) void gemm16(
    const float* __restrict__ X, const float* __restrict__ W,
    float* __restrict__ Cacc, int K, int N) {
    __shared__ __align__(16) float xs[16][KSL];
    const int tid = threadIdx.x;
    const int n = blockIdx.x * 64 + tid;
    const int k0 = blockIdx.y * KSL;
    for (int idx = tid; idx < 16 * KSL; idx += 64) {
        int b = idx >> 7;
        int k = idx & (KSL - 1);
        xs[b][k] = X[(size_t)b * K + k0 + k];
    }
    __syncthreads();
    float acc[16] = {};
    for (int k = 0; k < KSL; k += 4) {
        const float* wp = W + (size_t)(k0 + k) * N + n;
        float w0 = wp[0], w1 = wp[N], w2 = wp[2 * (size_t)N], w3 = wp[3 * (size_t)N];
#pragma unroll
        for (int b = 0; b < 16; ++b) {
            float4 xv = *(const float4*)&xs[b][k];
            acc[b] = fmaf(xv.x, w0, fmaf(xv.y, w1, fmaf(xv.z, w2, fmaf(xv.w, w3, acc[b]))));
        }
    }
#pragma unroll
    for (int b = 0; b < 16; ++b)
        atomicAdd(&Cacc[(size_t)b * N + n], acc[b]);
}

// ---------------------------------------------------------------------------
// Self-attention, flash-decode split: grid (H, B, NS). Each block handles a
// CH=128 chunk of the T axis; writes partial {m, s, acc[64]} to part_ws.
// Keys: cache[0..1022] + (k_new+bk) at t=1023.
// ---------------------------------------------------------------------------
__global__ __launch_bounds__(128) void attn_self_part(
    const float* __restrict__ q_raw, const float* __restrict__ bq,
    const float* __restrict__ kcache, const float* __restrict__ k_new,
    const float* __restrict__ bk,
    const float* __restrict__ vcache, const float* __restrict__ v_new,
    const float* __restrict__ bv, float* __restrict__ part) {
    const int h = blockIdx.x, b = blockIdx.y, z = blockIdx.z;
    const int tid = threadIdx.x;
    __shared__ __align__(16) float q[64];
    __shared__ float sc[CH];
    __shared__ float red[128];
    if (tid < 64) q[tid] = q_raw[b * DD + h * 64 + tid] + bq[h * 64 + tid];
    __syncthreads();
    const size_t bh = (size_t)(b * HH + h);
    const int t = z * CH + tid;
    float dot = 0.f;
    if (t < TPAST) {
        const float4* kr = (const float4*)(kcache + (bh * TPAST + t) * HDIM);
        const float4* q4 = (const float4*)q;
#pragma unroll
        for (int i = 0; i < 16; ++i) {
            float4 kv = kr[i], qv = q4[i];
            dot += qv.x * kv.x + qv.y * kv.y + qv.z * kv.z + qv.w * kv.w;
        }
    } else {
        for (int i = 0; i < 64; ++i)
            dot += q[i] * (k_new[b * DD + h * 64 + i] + bk[h * 64 + i]);
    }
    const float sval = dot * ASCALE;
    red[tid] = sval;
    __syncthreads();
    for (int s = 64; s > 0; s >>= 1) {
        if (tid < s) red[tid] = fmaxf(red[tid], red[tid + s]);
        __syncthreads();
    }
    const float mx = red[0];
    __syncthreads();
    const float pv = __expf(sval - mx);
    sc[tid] = pv;
    red[tid] = pv;
    __syncthreads();
    for (int s = 64; s > 0; s >>= 1) {
        if (tid < s) red[tid] += red[tid + s];
        __syncthreads();
    }
    const float ssum = red[0];
    __syncthreads();
    // V phase: hd = lane over 64 dims, 2 partial sums over t
    const int hd = tid & 63, prt = tid >> 6;
    float acc = 0.f;
    for (int tl = prt; tl < CH; tl += 2) {
        const int tg = z * CH + tl;
        float v;
        if (tg < TPAST) v = vcache[(bh * TPAST + tg) * HDIM + hd];
        else            v = v_new[b * DD + h * 64 + hd] + bv[h * 64 + hd];
        acc += sc[tl] * v;
    }
    red[tid] = acc;
    __syncthreads();
    float* pw = part + (bh * NS + z) * 66;
    if (tid < 64) pw[2 + tid] = red[tid] + red[64 + tid];
    if (tid == 0) { pw[0] = mx; pw[1] = ssum; }
}

// combine NS partials per (b,h): one 64-thread block per bh
__global__ __launch_bounds__(64) void attn_self_comb(
    const float* __restrict__ part, float* __restrict__ out) {
    const int bh = blockIdx.x;
    const int tid = threadIdx.x;
    float M = -1e30f;
#pragma unroll
    for (int z = 0; z < NS; ++z)
        M = fmaxf(M, part[(size_t)(bh * NS + z) * 66]);
    float S = 0.f, acc = 0.f;
#pragma unroll
    for (int z = 0; z < NS; ++z) {
        const float* pz = part + (size_t)(bh * NS + z) * 66;
        const float w = __expf(pz[0] - M);
        S += pz[1] * w;
        acc += pz[2 + tid] * w;
    }
    out[(size_t)bh * 64 + tid] = acc / S;   // b*DD + h*64 == bh*64
}

// ---------------------------------------------------------------------------
// Low-rank cross-attention (query length 1 => never materialize K_enc/V_enc):
//   rk[din]    = sum_d q'[d] * Wk[din, h*64+d]          (bk term cancels in SM)
//   score[s]   = (enc[b,s,:] . rk) * ASCALE
//   p          = softmax(score)
//   ctx[din]   = sum_s p[s] * enc[b,s,din]
//   out[h*64+d]= ctx . Wv[:, h*64+d] + bv[h*64+d]
// One 1024-thread block per (h, b). All fp32.
// ---------------------------------------------------------------------------
__global__ __launch_bounds__(1024) void cross_attn_lr(
    const float* __restrict__ q_raw, const float* __restrict__ bq,
    const float* __restrict__ Wk, const float* __restrict__ Wv,
    const float* __restrict__ bv, const float* __restrict__ enc,
    float* __restrict__ out) {
    const int h = blockIdx.x, b = blockIdx.y;
    const int tid = threadIdx.x;
    __shared__ __align__(16) float qs[64];
    __shared__ __align__(16) float rks[DD];
    __shared__ float p[SENC];
    __shared__ float red[1024];
    if (tid < 64) qs[tid] = q_raw[b * DD + h * 64 + tid] + bq[h * 64 + tid];
    __syncthreads();
    // rk: thread tid owns din = tid
    {
        const float4* wr = (const float4*)(Wk + (size_t)tid * DD + h * 64);
        const float4* q4 = (const float4*)qs;
        float acc = 0.f;
#pragma unroll
        for (int i = 0; i < 16; ++i) {
            float4 w = wr[i], q = q4[i];
            acc += q.x * w.x + q.y * w.y + q.z * w.z + q.w * w.w;
        }
        rks[tid] = acc;
    }
    __syncthreads();
    // scores: thread tid owns s = tid
    const float* eb = enc + (size_t)b * SENC * DD;
    float sval;
    {
        const float4* er = (const float4*)(eb + (size_t)tid * DD);
        const float4* r4 = (const float4*)rks;
        float dot = 0.f;
        for (int i = 0; i < 256; ++i) {
            float4 e = er[i], r = r4[i];
            dot += e.x * r.x + e.y * r.y + e.z * r.z + e.w * r.w;
        }
        sval = dot * ASCALE;
        red[tid] = sval;
    }
    __syncthreads();
    for (int s = 512; s > 0; s >>= 1) {
        if (tid < s) red[tid] = fmaxf(red[tid], red[tid + s]);
        __syncthreads();
    }
    const float mx = red[0];
    __syncthreads();
    const float pv = __expf(sval - mx);
    p[tid] = pv;
    red[tid] = pv;
    __syncthreads();
    for (int s = 512; s > 0; s >>= 1) {
        if (tid < s) red[tid] += red[tid + s];
        __syncthreads();
    }
    const float inv = 1.0f / red[0];
    __syncthreads();
    // ctx: thread tid owns din = tid (coalesced across lanes)
    float cacc = 0.f;
    for (int s = 0; s < SENC; s += 4) {
        const float p0 = p[s], p1 = p[s + 1], p2 = p[s + 2], p3 = p[s + 3];
        cacc += p0 * eb[(size_t)s * DD + tid];
        cacc += p1 * eb[(size_t)(s + 1) * DD + tid];
        cacc += p2 * eb[(size_t)(s + 2) * DD + tid];
        cacc += p3 * eb[(size_t)(s + 3) * DD + tid];
    }
    __syncthreads();           // p[] reads done before rks reuse
    rks[tid] = cacc * inv;     // normalized ctx
    __syncthreads();
    // vproj: wave w = part over din, lane d over 64 outputs
    const int d = tid & 63, part = tid >> 6;
    float oacc = 0.f;
    for (int din = part; din < DD; din += 16)
        oacc += rks[din] * Wv[(size_t)din * DD + h * 64 + d];
    red[tid] = oacc;
    __syncthreads();
    for (int s = 512; s >= 64; s >>= 1) {
        if (tid < s) red[tid] += red[tid + s];
        __syncthreads();
    }
    if (tid < 64)
        out[(size_t)b * DD + h * 64 + tid] = red[tid] + bv[h * 64 + tid];
}

// ---------------------------------------------------------------------------
// x[b,:] = LN(x[b,:] + a[b,:] + abias) * g + bb   (one block per b)
// ---------------------------------------------------------------------------
__global__ __launch_bounds__(256) void ln_kernel(
    float* __restrict__ x, const float* __restrict__ a,
    const float* __restrict__ ab, const float* __restrict__ g,
    const float* __restrict__ bb) {
    const int b = blockIdx.x, tid = threadIdx.x;
    __shared__ float buf[DD];
    __shared__ float red[256];
    float ls = 0.f, lq = 0.f;
    for (int i = tid; i < DD; i += 256) {
        float v = x[b * DD + i] + a[b * DD + i] + ab[i];
        buf[i] = v; ls += v; lq += v * v;
    }
    red[tid] = ls; __syncthreads();
    for (int s = 128; s > 0; s >>= 1) { if (tid < s) red[tid] += red[tid + s]; __syncthreads(); }
    const float mean = red[0] * (1.0f / DD);
    __syncthreads();
    red[tid] = lq; __syncthreads();
    for (int s = 128; s > 0; s >>= 1) { if (tid < s) red[tid] += red[tid + s]; __syncthreads(); }
    const float var = red[0] * (1.0f / DD) - mean * mean;
    const float rstd = rsqrtf(var + LNEPS);
    for (int i = tid; i < DD; i += 256)
        x[b * DD + i] = (buf[i] - mean) * rstd * g[i] + bb[i];
}

__global__ __launch_bounds__(256) void relu_bias(
    const float* __restrict__ raw, const float* __restrict__ b1,
    float* __restrict__ out) {
    for (int i = blockIdx.x * 256 + threadIdx.x; i < BB * FFD; i += gridDim.x * 256)
        out[i] = fmaxf(0.f, raw[i] + b1[i & (FFD - 1)]);
}

// one block (64 threads) per (b, v) output logit
__global__ __launch_bounds__(64) void logits_kernel(
    const float* __restrict__ x, const float* __restrict__ w_out,
    const float* __restrict__ b_out, float* __restrict__ out) {
    const int b = blockIdx.x / VOUT, v = blockIdx.x % VOUT;
    const int tid = threadIdx.x;
    float acc = 0.f;
    for (int k = tid; k < DD; k += 64)
        acc += x[b * DD + k] * w_out[(size_t)k * VOUT + v];
    for (int s = 32; s > 0; s >>= 1) acc += __shfl_down(acc, s);
    if (tid == 0) out[b * VOUT + v] = acc + b_out[v];
}

extern "C" void kernel_launch(void* const* d_in, const int* in_sizes, int n_in,
                              void* d_out, int out_size, void* d_ws, size_t ws_size,
                              hipStream_t stream) {
    const float* x_in    = (const float*)d_in[0];
    const float* enc     = (const float*)d_in[1];
    const float* k_cache = (const float*)d_in[2];
    const float* v_cache = (const float*)d_in[3];
    const float* wq_s = (const float*)d_in[4];  const float* bq_s = (const float*)d_in[5];
    const float* wk_s = (const float*)d_in[6];  const float* bk_s = (const float*)d_in[7];
    const float* wv_s = (const float*)d_in[8];  const float* bv_s = (const float*)d_in[9];
    const float* wo_s = (const float*)d_in[10]; const float* bo_s = (const float*)d_in[11];
    const float* wq_c = (const float*)d_in[12]; const float* bq_c = (const float*)d_in[13];
    const float* wk_c = (const float*)d_in[14]; const float* bk_c = (const float*)d_in[15];
    const float* wv_c = (const float*)d_in[16]; const float* bv_c = (const float*)d_in[17];
    const float* wo_c = (const float*)d_in[18]; const float* bo_c = (const float*)d_in[19];
    const float* w1 = (const float*)d_in[20];   const float* b1 = (const float*)d_in[21];
    const float* w2 = (const float*)d_in[22];   const float* b2 = (const float*)d_in[23];
    const float* ln1_g = (const float*)d_in[24]; const float* ln1_b = (const float*)d_in[25];
    const float* ln2_g = (const float*)d_in[26]; const float* ln2_b = (const float*)d_in[27];
    const float* ln3_g = (const float*)d_in[28]; const float* ln3_b = (const float*)d_in[29];
    const float* w_out = (const float*)d_in[30]; const float* b_out = (const float*)d_in[31];
    float* out = (float*)d_out;
    (void)bk_c;   // bk_c.q term is constant over s -> cancels exactly in softmax

    float* ws = (float*)d_ws;
    float* x_buf   = ws;            // 16384
    float* mm_q    = ws + 16384;    // 16384
    float* mm_k    = ws + 32768;    // 16384
    float* mm_v    = ws + 49152;    // 16384
    float* attn_o  = ws + 65536;    // 16384
    float* mm_p    = ws + 81920;    // 16384
    float* mm_h1   = ws + 98304;    // 65536
    float* h1a     = ws + 163840;   // 65536
    float* part_ws = ws + 229376;   // 256*8*66 = 135168

    hipMemcpyAsync(x_buf, x_in, (size_t)BB * DD * sizeof(float),
                   hipMemcpyDeviceToDevice, stream);

    const dim3 gAttnP(HH, BB, NS);
    const dim3 gCross(HH, BB);

    for (int l = 0; l < NLAYER; ++l) {
        const size_t oM = (size_t)l * DD * DD;
        const size_t oV = (size_t)l * DD;
        const size_t oC = (size_t)l * BB * HH * TPAST * HDIM;

        // ---- self attention ----
        hipMemsetAsync(mm_q, 0, 3 * (size_t)BB * DD * sizeof(float), stream);
        gemm16<<<dim3(DD / 64, DD / KSL), 64, 0, stream>>>(x_buf, wq_s + oM, mm_q, DD, DD);
        gemm16<<<dim3(DD / 64, DD / KSL), 64, 0, stream>>>(x_buf, wk_s + oM, mm_k, DD, DD);
        gemm16<<<dim3(DD / 64, DD / KSL), 64, 0, stream>>>(x_buf, wv_s + oM, mm_v, DD, DD);
        attn_self_part<<<gAttnP, 128, 0, stream>>>(mm_q, bq_s + oV, k_cache + oC, mm_k,
                                                   bk_s + oV, v_cache + oC, mm_v, bv_s + oV,
                                                   part_ws);
        attn_self_comb<<<BB * HH, 64, 0, stream>>>(part_ws, attn_o);
        hipMemsetAsync(mm_p, 0, (size_t)BB * DD * sizeof(float), stream);
        gemm16<<<dim3(DD / 64, DD / KSL), 64, 0, stream>>>(attn_o, wo_s + oM, mm_p, DD, DD);
        ln_kernel<<<BB, 256, 0, stream>>>(x_buf, mm_p, bo_s + oV, ln1_g + oV, ln1_b + oV);

        // ---- cross attention (low-rank, no K/V materialization) ----
        hipMemsetAsync(mm_q, 0, (size_t)BB * DD * sizeof(float), stream);
        gemm16<<<dim3(DD / 64, DD / KSL), 64, 0, stream>>>(x_buf, wq_c + oM, mm_q, DD, DD);
        cross_attn_lr<<<gCross, 1024, 0, stream>>>(mm_q, bq_c + oV, wk_c + oM, wv_c + oM,
                                                   bv_c + oV, enc, attn_o);
        hipMemsetAsync(mm_p, 0, (size_t)BB * DD * sizeof(float), stream);
        gemm16<<<dim3(DD / 64, DD / KSL), 64, 0, stream>>>(attn_o, wo_c + oM, mm_p, DD, DD);
        ln_kernel<<<BB, 256, 0, stream>>>(x_buf, mm_p, bo_c + oV, ln2_g + oV, ln2_b + oV);

        // ---- FFN ----
        hipMemsetAsync(mm_h1, 0, (size_t)BB * FFD * sizeof(float), stream);
        gemm16<<<dim3(FFD / 64, DD / KSL), 64, 0, stream>>>(x_buf, w1 + (size_t)l * DD * FFD,
                                                            mm_h1, DD, FFD);
        relu_bias<<<64, 256, 0, stream>>>(mm_h1, b1 + (size_t)l * FFD, h1a);
        hipMemsetAsync(mm_p, 0, (size_t)BB * DD * sizeof(float), stream);
        gemm16<<<dim3(DD / 64, FFD / KSL), 64, 0, stream>>>(h1a, w2 + (size_t)l * FFD * DD,
                                                            mm_p, FFD, DD);
        ln_kernel<<<BB, 256, 0, stream>>>(x_buf, mm_p, b2 + oV, ln3_g + oV, ln3_b + oV);
    }

    logits_kernel<<<BB * VOUT, 64, 0, stream>>>(x_buf, w_out, b_out, out);
}